// Round 1
// baseline (1250.690 us; speedup 1.0000x reference)
//
#include <hip/hip_runtime.h>

// ChunkwiseDeltaAttention (MI355X/gfx950) — round 4
// B=4 L=4096 H=2048 NH=16 D=128 C=64 -> M=16384, K=2048
//
// Fast path:
//   beta_kernel: beta = softplus(hs @ b_w^T + b_b), AND hs -> bf16 hsb (fused)
//   cvt: {q,k,v,og}_w -> bf16 wcat [8192,2048]; o_w -> owb
//   gemm256<0,8192>: [qy|kn|gv|gate] = hsb @ wcat^T (+bias), fused epi
//   attn: l2norm in LDS, S=qk^T (MFMA), causal mask, O=S gv, *gate
//   gemm256<3,2048>: out = y @ o_w^T + o_b -> f32 d_out
//
// GEMM this round: 256x256 tile, BK=32, 512 thr / 8 waves (2Mx4N, 128x64/wave),
// 4-deep LDS ring (4x32KB=128KiB), counted s_waitcnt vmcnt(8) + raw s_barrier
// ONCE per K-tile (tile t+3 staged while computing tile t => ~3 tiles of
// latency cover; never vmcnt(0) in the loop). Each fragment ds_read exactly
// once per tile (B frags live in regs across both mi-phases): 12 b128/wave/
// tile vs 32 MFMA => MFMA-bound by design. setprio(1) around MFMA clusters.
// XOR chunk swizzle (16B chunks, c ^= row&3): linear global_load_lds dest,
// inverse swizzle on the global source, same swizzle on ds_read side.
// Tail: last 3 iters stage harmless reloads into the free ring slot so the
// in-loop vmcnt literal stays 8 (accounting proof in comments below).

typedef __bf16 bf16x8 __attribute__((ext_vector_type(8)));
typedef float f32x4 __attribute__((ext_vector_type(4)));

typedef __attribute__((address_space(1))) const unsigned int g_u32;
typedef __attribute__((address_space(3))) unsigned int l_u32;

__device__ __forceinline__ void cp16(const unsigned short* g, unsigned short* l) {
  __builtin_amdgcn_global_load_lds((g_u32*)g, (l_u32*)l, 16, 0, 0);
}

__device__ __forceinline__ unsigned short f2bf(float x) {
  unsigned u = __builtin_bit_cast(unsigned, x);
  u += 0x7fffu + ((u >> 16) & 1u);          // RNE
  return (unsigned short)(u >> 16);
}
__device__ __forceinline__ float bf2f(unsigned short h) {
  return __builtin_bit_cast(float, (unsigned)h << 16);
}
__device__ __forceinline__ unsigned pk2(float a, float b) {
  return (unsigned)f2bf(a) | ((unsigned)f2bf(b) << 16);
}

// ------------------------------------------------------------- convert ----
__global__ __launch_bounds__(256) void cvt_bf16(const float* __restrict__ in,
                                                unsigned short* __restrict__ out,
                                                int n) {
  int i = (blockIdx.x * 256 + threadIdx.x) * 8;
  if (i >= n) return;
  float4 f0 = *(const float4*)(in + i);
  float4 f1 = *(const float4*)(in + i + 4);
  uint4 u;
  u.x = pk2(f0.x, f0.y); u.y = pk2(f0.z, f0.w);
  u.z = pk2(f1.x, f1.y); u.w = pk2(f1.z, f1.w);
  *(uint4*)(out + i) = u;
}

__global__ __launch_bounds__(256) void build_bias(
    const float* __restrict__ qb, const float* __restrict__ kb,
    const float* __restrict__ vb, float* __restrict__ bias_cat) {
  int i = blockIdx.x * 256 + threadIdx.x;   // 0..8191
  float v = 0.f;
  if (i < 2048) v = qb[i];
  else if (i < 4096) v = kb[i - 2048];
  else if (i < 6144) v = vb[i - 4096];
  bias_cat[i] = v;
}

// ------------------------------------------------- beta (+ hs->bf16) ------
__global__ __launch_bounds__(256) void beta_kernel(
    const float* __restrict__ hs, const float* __restrict__ bw,
    const float* __restrict__ bb, float* __restrict__ beta,
    unsigned short* __restrict__ hsb) {
  __shared__ float row[2048];
  __shared__ float part[16][17];
  const int m = blockIdx.x;
  const float* src = hs + (size_t)m * 2048;
  for (int i = threadIdx.x; i < 512; i += 256)
    ((float4*)row)[i] = ((const float4*)src)[i];
  __syncthreads();
  if (hsb) {  // fused f32->bf16 of this row
    int e = threadIdx.x * 8;
    uint4 u;
    u.x = pk2(row[e], row[e + 1]);     u.y = pk2(row[e + 2], row[e + 3]);
    u.z = pk2(row[e + 4], row[e + 5]); u.w = pk2(row[e + 6], row[e + 7]);
    *(uint4*)(hsb + (size_t)m * 2048 + e) = u;
  }
  const int h = threadIdx.x >> 4, j = threadIdx.x & 15;
  const float* w = bw + h * 2048;
  float s = 0.f;
  #pragma unroll 8
  for (int kk = 0; kk < 128; kk++) {
    int k = j + (kk << 4);
    s += row[k] * w[k];
  }
  part[h][j] = s;
  __syncthreads();
  if (threadIdx.x < 16) {
    int hh = threadIdx.x;
    float t = bb[hh];
    #pragma unroll
    for (int j2 = 0; j2 < 16; j2++) t += part[hh][j2];
    beta[(size_t)m * 16 + hh] = fmaxf(t, 0.f) + log1pf(__expf(-fabsf(t)));
  }
}

// -------------------------------------------- GEMM 256x256, counted vmcnt --
// C[m,n] = sum_k A[m,k]*B[n,k], bf16 in. 512 threads = 8 waves (2Mx4N).
// LDS ring: As/Bs[4 bufs][256 rows][32 cols] bf16 (16KB per matrix per buf).
// Schedule per K-tile t (cur=t&3, nb=(t+3)&3):
//   phase A: issue A-stage(t+3)->buf nb; ds_read A mi0-3 + B ni0-3 (8xb128);
//            setprio(1); 16 MFMA; setprio(0)
//   phase B: issue B-stage(t+3);         ds_read A mi4-7 (4xb128, B in regs);
//            setprio(1); 16 MFMA; setprio(0)
//   boundary (t != NT-1): s_waitcnt vmcnt(8); s_barrier
// vmcnt proof: outstanding at boundary = tiles t+1(4),t+2(4),t+3(4)=12; in-
// order drain to 8 leaves {t+2,t+3} => t+1 confirmed complete everywhere
// after the barrier. Buffer nb was last read at tile t-1 (before the t-1
// boundary barrier), so staging into it during tile t is race-free.
// Tail (t+3>=NT): stage reloads of tile NT-1's columns into the (free) nb
// slot, keeping the accounting uniform; drained by vmcnt(0) before epilogue.
template <int EPI, int N, int K>
__global__ __launch_bounds__(512, 2) void gemm256(
    const unsigned short* __restrict__ A, const unsigned short* __restrict__ Bw,
    const float* __restrict__ bias, const float* __restrict__ beta,
    void* __restrict__ Cv) {
  constexpr int NT = K / 32;
  __shared__ __align__(16) unsigned short As[4 * 8192];
  __shared__ __align__(16) unsigned short Bs[4 * 8192];
  const int tid = threadIdx.x;
  const int m0 = blockIdx.y * 256;
  const int n0 = blockIdx.x * 256;
  const int wid = tid >> 6, lane = tid & 63;
  const int wm = wid >> 2, wn = wid & 3;
  const int quad = lane >> 4, l16 = lane & 15;

  // staging: thread t covers rows trow and trow+128, 16B chunk p=t&3 of the
  // 64B row; source column is the XOR-swizzled chunk l = p ^ (row&3).
  const int trow = tid >> 2;
  const int tch = ((tid & 3) ^ (trow & 3)) << 3;        // element offset
  const unsigned short* Ag = A + (size_t)(m0 + trow) * K + tch;
  const unsigned short* Bg = Bw + (size_t)(n0 + trow) * K + tch;

  // ds_read side: physical chunk = quad ^ (row&3); row&3 == l16&3 here.
  const int chs = (quad ^ (l16 & 3)) << 4;              // byte offset
  const int a_lane = (wm * 128 + l16) * 64 + chs;
  const int b_lane = (wn * 64 + l16) * 64 + chs;

  f32x4 acc[8][4] = {};

  // prologue: stage tiles 0,1,2 (A,A,B,B per tile, in tile order)
  #pragma unroll
  for (int tt = 0; tt < 3; ++tt) {
    const size_t kk = (size_t)tt * 32;
    unsigned short* la = As + tt * 8192 + tid * 8;
    unsigned short* lb = Bs + tt * 8192 + tid * 8;
    cp16(Ag + kk, la);
    cp16(Ag + (size_t)128 * K + kk, la + 4096);
    cp16(Bg + kk, lb);
    cp16(Bg + (size_t)128 * K + kk, lb + 4096);
  }
  asm volatile("s_waitcnt vmcnt(8)" ::: "memory");   // tile 0 complete
  __builtin_amdgcn_s_barrier();

  for (int t = 0; t < NT; ++t) {
    const int cur = t & 3;
    const int nb = (t + 3) & 3;
    const size_t k3 = (size_t)((t + 3 < NT) ? (t + 3) : (NT - 1)) * 32;
    const char* At = (const char*)As + cur * 16384 + a_lane;
    const char* Bt = (const char*)Bs + cur * 16384 + b_lane;
    unsigned short* la = As + nb * 8192 + tid * 8;
    unsigned short* lb = Bs + nb * 8192 + tid * 8;

    // ---- phase A: stage next A, compute mi 0..3 x ni 0..3 ----
    cp16(Ag + k3, la);
    cp16(Ag + (size_t)128 * K + k3, la + 4096);
    bf16x8 af[4], bfr[4];
    #pragma unroll
    for (int mi = 0; mi < 4; mi++) af[mi] = *(const bf16x8*)(At + mi * 1024);
    #pragma unroll
    for (int ni = 0; ni < 4; ni++) bfr[ni] = *(const bf16x8*)(Bt + ni * 1024);
    __builtin_amdgcn_s_setprio(1);
    #pragma unroll
    for (int mi = 0; mi < 4; mi++)
      #pragma unroll
      for (int ni = 0; ni < 4; ni++)
        acc[mi][ni] = __builtin_amdgcn_mfma_f32_16x16x32_bf16(
            af[mi], bfr[ni], acc[mi][ni], 0, 0, 0);
    __builtin_amdgcn_s_setprio(0);

    // ---- phase B: stage next B, compute mi 4..7 (B frags held in regs) ----
    cp16(Bg + k3, lb);
    cp16(Bg + (size_t)128 * K + k3, lb + 4096);
    #pragma unroll
    for (int mi = 0; mi < 4; mi++) af[mi] = *(const bf16x8*)(At + (4 + mi) * 1024);
    __builtin_amdgcn_s_setprio(1);
    #pragma unroll
    for (int mi = 0; mi < 4; mi++)
      #pragma unroll
      for (int ni = 0; ni < 4; ni++)
        acc[4 + mi][ni] = __builtin_amdgcn_mfma_f32_16x16x32_bf16(
            af[mi], bfr[ni], acc[4 + mi][ni], 0, 0, 0);
    __builtin_amdgcn_s_setprio(0);

    if (t != NT - 1) {
      asm volatile("s_waitcnt vmcnt(8)" ::: "memory");
      __builtin_amdgcn_s_barrier();
    }
  }
  // drain tail garbage stages before LDS goes out of scope / epilogue
  asm volatile("s_waitcnt vmcnt(0)" ::: "memory");

  // epilogue; C/D layout: col=lane&15, row=quad*4+reg
  if (EPI == 0) {
    const int mode = n0 >> 11;              // 0:q 1:k 2:v 3:gate (256 | 2048)
    unsigned short* outp =
        (unsigned short*)Cv + (size_t)mode * ((size_t)16384 * 2048);
    const int head = ((n0 + wn * 64) >> 7) & 15;   // head uniform per wave
    #pragma unroll
    for (int mi = 0; mi < 8; mi++) {
      #pragma unroll
      for (int r = 0; r < 4; r++) {
        const int row = m0 + wm * 128 + mi * 16 + quad * 4 + r;
        const float bsc = (mode == 2) ? beta[(size_t)row * 16 + head] : 1.f;
        #pragma unroll
        for (int ni = 0; ni < 4; ni++) {
          const int col = n0 + wn * 64 + ni * 16 + l16;
          float x = acc[mi][ni][r] + bias[col];
          if (mode == 2) x *= bsc;
          if (mode == 3) x = x / (1.f + __expf(-x));
          __builtin_nontemporal_store(
              f2bf(x), &outp[(size_t)row * 2048 + (col & 2047)]);
        }
      }
    }
  } else {
    #pragma unroll
    for (int mi = 0; mi < 8; mi++)
      #pragma unroll
      for (int r = 0; r < 4; r++) {
        const int row = m0 + wm * 128 + mi * 16 + quad * 4 + r;
        #pragma unroll
        for (int ni = 0; ni < 4; ni++) {
          const int col = n0 + wn * 64 + ni * 16 + l16;
          __builtin_nontemporal_store(
              acc[mi][ni][r] + bias[col],
              &((float*)Cv)[(size_t)row * N + col]);
        }
      }
  }
}

// --------------------------------------------- fallback GEMM (round 1) ----
constexpr int GLDW = 40;
template <int EPI, bool ABF16>
__global__ __launch_bounds__(256) void gemm_bt(
    const void* __restrict__ Av, const float* __restrict__ Bw,
    const float* __restrict__ bias, const float* __restrict__ beta,
    void* __restrict__ Cv, int M, int N, int K) {
  __shared__ unsigned short As[128 * GLDW];
  __shared__ unsigned short Bs[128 * GLDW];
  const int tid = threadIdx.x;
  const int m0 = blockIdx.y * 128;
  const int n0 = blockIdx.x * 128;
  const int wid = tid >> 6, lane = tid & 63;
  const int wm = wid >> 1, wn = wid & 1;
  const int quad = lane >> 4, l16 = lane & 15;
  const int srow = tid >> 1, skh = (tid & 1) << 4;

  f32x4 acc[4][4] = {};
  const float* Bg = Bw + (size_t)(n0 + srow) * K + skh;

  for (int kb = 0; kb < K; kb += 32) {
    if (ABF16) {
      const unsigned short* Ag =
          (const unsigned short*)Av + (size_t)(m0 + srow) * K + kb + skh;
      uint4 u0 = ((const uint4*)Ag)[0];
      uint4 u1 = ((const uint4*)Ag)[1];
      uint4* d = (uint4*)&As[srow * GLDW + skh];
      d[0] = u0; d[1] = u1;
    } else {
      const float* Ag = (const float*)Av + (size_t)(m0 + srow) * K + kb + skh;
      float4 f0 = ((const float4*)Ag)[0];
      float4 f1 = ((const float4*)Ag)[1];
      float4 f2 = ((const float4*)Ag)[2];
      float4 f3 = ((const float4*)Ag)[3];
      unsigned* d = (unsigned*)&As[srow * GLDW + skh];
      d[0] = pk2(f0.x, f0.y); d[1] = pk2(f0.z, f0.w);
      d[2] = pk2(f1.x, f1.y); d[3] = pk2(f1.z, f1.w);
      d[4] = pk2(f2.x, f2.y); d[5] = pk2(f2.z, f2.w);
      d[6] = pk2(f3.x, f3.y); d[7] = pk2(f3.z, f3.w);
    }
    {
      const float* Bgk = Bg + kb;
      float4 f0 = ((const float4*)Bgk)[0];
      float4 f1 = ((const float4*)Bgk)[1];
      float4 f2 = ((const float4*)Bgk)[2];
      float4 f3 = ((const float4*)Bgk)[3];
      unsigned* d = (unsigned*)&Bs[srow * GLDW + skh];
      d[0] = pk2(f0.x, f0.y); d[1] = pk2(f0.z, f0.w);
      d[2] = pk2(f1.x, f1.y); d[3] = pk2(f1.z, f1.w);
      d[4] = pk2(f2.x, f2.y); d[5] = pk2(f2.z, f2.w);
      d[6] = pk2(f3.x, f3.y); d[7] = pk2(f3.z, f3.w);
    }
    __syncthreads();
    bf16x8 af[4], bfr[4];
    #pragma unroll
    for (int mi = 0; mi < 4; mi++)
      af[mi] = *(const bf16x8*)&As[(wm * 64 + mi * 16 + l16) * GLDW + (quad << 3)];
    #pragma unroll
    for (int ni = 0; ni < 4; ni++)
      bfr[ni] = *(const bf16x8*)&Bs[(wn * 64 + ni * 16 + l16) * GLDW + (quad << 3)];
    #pragma unroll
    for (int mi = 0; mi < 4; mi++)
      #pragma unroll
      for (int ni = 0; ni < 4; ni++)
        acc[mi][ni] = __builtin_amdgcn_mfma_f32_16x16x32_bf16(
            af[mi], bfr[ni], acc[mi][ni], 0, 0, 0);
    __syncthreads();
  }

  #pragma unroll
  for (int mi = 0; mi < 4; mi++) {
    #pragma unroll
    for (int r = 0; r < 4; r++) {
      const int row = m0 + wm * 64 + mi * 16 + quad * 4 + r;
      float bsc = 1.f;
      if (EPI == 1) bsc = beta[(size_t)row * 16 + blockIdx.x];
      #pragma unroll
      for (int ni = 0; ni < 4; ni++) {
        const int col = n0 + wn * 64 + ni * 16 + l16;
        float x = acc[mi][ni][r];
        if (EPI != 2) x += bias[col];
        if (EPI == 1) x *= bsc;
        if (EPI == 2) x = x / (1.f + __expf(-x));
        if (EPI == 3)
          ((float*)Cv)[(size_t)row * N + col] = x;
        else
          ((unsigned short*)Cv)[(size_t)row * N + col] = f2bf(x);
      }
    }
  }
}

// ----------------------------------------------------------- attention ----
constexpr int QK_LDW = 132;  // 264B = 66 banks = 2 mod 32: lanes spread
constexpr int GT_LDW = 66;   // 132B = 33 banks = 1 mod 32: write 16-way -> 4-way
constexpr int SS_LDW = 68;   // 136B = 34 banks = 2 mod 32

__global__ __launch_bounds__(256) void attn_kernel(
    const unsigned short* __restrict__ qn, const unsigned short* __restrict__ kn,
    const unsigned short* __restrict__ gvp, const unsigned short* __restrict__ gate,
    unsigned short* __restrict__ y) {
  __shared__ unsigned short qs[64 * QK_LDW];
  __shared__ unsigned short ks[64 * QK_LDW];
  __shared__ unsigned short gst[128 * GT_LDW];
  __shared__ unsigned short Ss[64 * SS_LDW];

  const int tid = threadIdx.x;
  const int m0 = blockIdx.x * 64;
  const int h = blockIdx.y;
  const size_t gbase = (size_t)m0 * 2048 + (size_t)h * 128;

  #pragma unroll
  for (int it = 0; it < 4; it++) {
    int e = tid + it * 256;
    int i = e >> 4;
    int c = (e & 15) << 3;
    size_t g = gbase + (size_t)i * 2048 + c;
    *(uint4*)&qs[i * QK_LDW + c] = *(const uint4*)&qn[g];
    *(uint4*)&ks[i * QK_LDW + c] = *(const uint4*)&kn[g];
    uint4 gvv = *(const uint4*)&gvp[g];
    unsigned short tmp[8];
    *(uint4*)tmp = gvv;
    #pragma unroll
    for (int t = 0; t < 8; t++) gst[(c + t) * GT_LDW + i] = tmp[t];
  }
  __syncthreads();

  {
    const int rr = tid >> 2;
    const int seg = (tid & 3) * 32;
    float ssq = 0.f, ssk = 0.f;
    #pragma unroll
    for (int k2 = 0; k2 < 32; k2 += 2) {
      unsigned uq = *(const unsigned*)&qs[rr * QK_LDW + seg + k2];
      unsigned uk = *(const unsigned*)&ks[rr * QK_LDW + seg + k2];
      float a = bf2f((unsigned short)(uq & 0xffff)), b = bf2f((unsigned short)(uq >> 16));
      float c2 = bf2f((unsigned short)(uk & 0xffff)), d2 = bf2f((unsigned short)(uk >> 16));
      ssq += a * a + b * b;
      ssk += c2 * c2 + d2 * d2;
    }
    ssq += __shfl_xor(ssq, 1); ssq += __shfl_xor(ssq, 2);
    ssk += __shfl_xor(ssk, 1); ssk += __shfl_xor(ssk, 2);
    float iq = rsqrtf(fmaxf(ssq, 1e-24f));
    float ik = rsqrtf(fmaxf(ssk, 1e-24f));
    #pragma unroll
    for (int k2 = 0; k2 < 32; k2 += 2) {
      unsigned uq = *(const unsigned*)&qs[rr * QK_LDW + seg + k2];
      unsigned uk = *(const unsigned*)&ks[rr * QK_LDW + seg + k2];
      float a = bf2f((unsigned short)(uq & 0xffff)), b = bf2f((unsigned short)(uq >> 16));
      float c2 = bf2f((unsigned short)(uk & 0xffff)), d2 = bf2f((unsigned short)(uk >> 16));
      *(unsigned*)&qs[rr * QK_LDW + seg + k2] = pk2(a * iq, b * iq);
      *(unsigned*)&ks[rr * QK_LDW + seg + k2] = pk2(c2 * ik, d2 * ik);
    }
  }
  __syncthreads();

  const int w = tid >> 6;
  const int lane = tid & 63;
  const int quad = lane >> 4, l16 = lane & 15;

  {
    f32x4 acc[4] = {};
    #pragma unroll
    for (int kst = 0; kst < 4; kst++) {
      bf16x8 a = *(const bf16x8*)&qs[(w * 16 + l16) * QK_LDW + kst * 32 + (quad << 3)];
      #pragma unroll
      for (int ni = 0; ni < 4; ni++) {
        bf16x8 b = *(const bf16x8*)&ks[(ni * 16 + l16) * QK_LDW + kst * 32 + (quad << 3)];
        acc[ni] = __builtin_amdgcn_mfma_f32_16x16x32_bf16(a, b, acc[ni], 0, 0, 0);
      }
    }
    #pragma unroll
    for (int ni = 0; ni < 4; ni++)
      #pragma unroll
      for (int r = 0; r < 4; r++) {
        int row = w * 16 + quad * 4 + r;
        int col = ni * 16 + l16;
        float val = (col <= row) ? acc[ni][r] : 0.f;
        Ss[row * SS_LDW + col] = f2bf(val);
      }
  }
  __syncthreads();

  {
    f32x4 acc[8] = {};
    #pragma unroll
    for (int kst = 0; kst < 2; kst++) {
      bf16x8 a = *(const bf16x8*)&Ss[(w * 16 + l16) * SS_LDW + kst * 32 + (quad << 3)];
      #pragma unroll
      for (int nd = 0; nd < 8; nd++) {
        bf16x8 b = *(const bf16x8*)&gst[(nd * 16 + l16) * GT_LDW + kst * 32 + (quad << 3)];
        acc[nd] = __builtin_amdgcn_mfma_f32_16x16x32_bf16(a, b, acc[nd], 0, 0, 0);
      }
    }
    #pragma unroll
    for (int nd = 0; nd < 8; nd++)
      #pragma unroll
      for (int r = 0; r < 4; r++) {
        int row = w * 16 + quad * 4 + r;
        int col = nd * 16 + l16;
        size_t g = gbase + (size_t)row * 2048 + col;
        float gt = bf2f(gate[g]);
        y[g] = f2bf(acc[nd][r] * gt);
      }
  }
}

// --------------------------------------------------------------- launch ---
extern "C" void kernel_launch(void* const* d_in, const int* in_sizes, int n_in,
                              void* d_out, int out_size, void* d_ws, size_t ws_size,
                              hipStream_t stream) {
  const float* hs   = (const float*)d_in[0];
  const float* q_w  = (const float*)d_in[1];
  const float* q_b  = (const float*)d_in[2];
  const float* k_w  = (const float*)d_in[3];
  const float* k_b  = (const float*)d_in[4];
  const float* v_w  = (const float*)d_in[5];
  const float* v_b  = (const float*)d_in[6];
  const float* b_w  = (const float*)d_in[9];
  const float* b_b  = (const float*)d_in[10];
  const float* og_w = (const float*)d_in[11];
  const float* o_w  = (const float*)d_in[12];
  const float* o_b  = (const float*)d_in[13];

  const int M = 16384, K = 2048;
  const size_t MB64 = 67108864;         // one [M,2048] bf16 buffer

  const size_t OFF_HSB  = 4 * MB64;
  const size_t OFF_WCAT = OFF_HSB + MB64;
  const size_t OFF_OWB  = OFF_WCAT + 33554432;
  const size_t OFF_BETA = OFF_OWB + 8388608;
  const size_t OFF_BIAS = OFF_BETA + 1048576;
  const size_t NEED     = OFF_BIAS + 32768;

  char* ws = (char*)d_ws;

  if (ws_size >= NEED) {
    unsigned short* qy   = (unsigned short*)ws;
    unsigned short* knb  = (unsigned short*)(ws + MB64);
    unsigned short* gv   = (unsigned short*)(ws + 2 * MB64);
    unsigned short* gate = (unsigned short*)(ws + 3 * MB64);
    unsigned short* hsb  = (unsigned short*)(ws + OFF_HSB);
    unsigned short* wcat = (unsigned short*)(ws + OFF_WCAT);
    unsigned short* owb  = (unsigned short*)(ws + OFF_OWB);
    float*          beta = (float*)(ws + OFF_BETA);
    float*          bias = (float*)(ws + OFF_BIAS);

    const int NW = 4194304;  // elems per 2048x2048 weight
    cvt_bf16<<<NW / 2048, 256, 0, stream>>>(q_w,  wcat,          NW);
    cvt_bf16<<<NW / 2048, 256, 0, stream>>>(k_w,  wcat + NW,     NW);
    cvt_bf16<<<NW / 2048, 256, 0, stream>>>(v_w,  wcat + 2 * NW, NW);
    cvt_bf16<<<NW / 2048, 256, 0, stream>>>(og_w, wcat + 3 * NW, NW);
    cvt_bf16<<<NW / 2048, 256, 0, stream>>>(o_w,  owb,           NW);
    build_bias<<<32, 256, 0, stream>>>(q_b, k_b, v_b, bias);
    beta_kernel<<<M, 256, 0, stream>>>(hs, b_w, b_b, beta, hsb);  // + hs->bf16

    gemm256<0, 8192, 2048><<<dim3(32, 64), 512, 0, stream>>>(
        hsb, wcat, bias, beta, qy);

    attn_kernel<<<dim3(256, 16), 256, 0, stream>>>(qy, knb, gv, gate, qy);

    gemm256<3, 2048, 2048><<<dim3(8, 64), 512, 0, stream>>>(
        qy, owb, o_b, nullptr, (float*)d_out);
  } else {
    // round-1 fallback (f32 pack staging), known-correct
    unsigned short* qy   = (unsigned short*)ws;
    unsigned short* knb  = (unsigned short*)(ws + MB64);
    unsigned short* gv   = (unsigned short*)(ws + 2 * MB64);
    unsigned short* gate = (unsigned short*)(ws + 3 * MB64);
    float*          beta = (float*)(ws + 4 * MB64);

    beta_kernel<<<M, 256, 0, stream>>>(hs, b_w, b_b, beta, nullptr);
    dim3 gg(16, 128);
    gemm_bt<0, false><<<gg, 256, 0, stream>>>(hs, q_w, q_b, nullptr, qy, M, 2048, K);
    gemm_bt<0, false><<<gg, 256, 0, stream>>>(hs, k_w, k_b, nullptr, knb, M, 2048, K);
    gemm_bt<1, false><<<gg, 256, 0, stream>>>(hs, v_w, v_b, beta, gv, M, 2048, K);
    gemm_bt<2, false><<<gg, 256, 0, stream>>>(hs, og_w, nullptr, nullptr, gate, M, 2048, K);
    attn_kernel<<<dim3(256, 16), 256, 0, stream>>>(qy, knb, gv, gate, qy);
    gemm_bt<3, true><<<gg, 256, 0, stream>>>(qy, o_w, o_b, nullptr, (float*)d_out, M, 2048, K);
  }
}

// Round 2
// 1227.954 us; speedup vs baseline: 1.0185x; 1.0185x over previous
//
#include <hip/hip_runtime.h>

// ChunkwiseDeltaAttention (MI355X/gfx950) — round 5
// B=4 L=4096 H=2048 NH=16 D=128 C=64 -> M=16384, K=2048
//
// Fast path:
//   beta_kernel: beta = softplus(hs @ b_w^T + b_b), AND hs -> bf16 hsb (fused)
//   cvt: {q,k,v,og}_w -> bf16 wcat [8192,2048]; o_w -> owb
//   gemm256<0,8192>: [qy|kn|gv|gate] = hsb @ wcat^T (+bias), fused epi
//   attn: l2norm in LDS, S=qk^T (MFMA), causal mask, O=S gv, *gate
//   gemm256<3,2048>: out = y @ o_w^T + o_b -> f32 d_out
//
// GEMM: 256x256 tile, BK=32, 512 thr / 8 waves (2Mx4N, 128x64/wave),
// 4-deep LDS ring (4x32KB=128KiB), counted s_waitcnt vmcnt(8) + raw s_barrier
// ONCE per K-tile. Round-5 fix vs round-4: XOR swizzle uses sigma(row) =
// (row>>1)&3 (round-4's row&3 aliased lanes {0..3}/{4..7} onto the same four
// 16B slots within each 128B bank group -> 5e7 conflicts, MfmaUtil 35%).
// Conflict-free check (8-lane group, quad q): addr mod 128 =
// 64*(l16&1) + 16*(q ^ ((l16>>1)&3)) -> all 8 slots distinct.
// Also removed nontemporal C stores (round-4: +200MB HBM write, evicted the
// intermediate that attn/gemm<3> re-read).

typedef __bf16 bf16x8 __attribute__((ext_vector_type(8)));
typedef float f32x4 __attribute__((ext_vector_type(4)));

typedef __attribute__((address_space(1))) const unsigned int g_u32;
typedef __attribute__((address_space(3))) unsigned int l_u32;

__device__ __forceinline__ void cp16(const unsigned short* g, unsigned short* l) {
  __builtin_amdgcn_global_load_lds((g_u32*)g, (l_u32*)l, 16, 0, 0);
}

__device__ __forceinline__ unsigned short f2bf(float x) {
  unsigned u = __builtin_bit_cast(unsigned, x);
  u += 0x7fffu + ((u >> 16) & 1u);          // RNE
  return (unsigned short)(u >> 16);
}
__device__ __forceinline__ float bf2f(unsigned short h) {
  return __builtin_bit_cast(float, (unsigned)h << 16);
}
__device__ __forceinline__ unsigned pk2(float a, float b) {
  return (unsigned)f2bf(a) | ((unsigned)f2bf(b) << 16);
}

// ------------------------------------------------------------- convert ----
__global__ __launch_bounds__(256) void cvt_bf16(const float* __restrict__ in,
                                                unsigned short* __restrict__ out,
                                                int n) {
  int i = (blockIdx.x * 256 + threadIdx.x) * 8;
  if (i >= n) return;
  float4 f0 = *(const float4*)(in + i);
  float4 f1 = *(const float4*)(in + i + 4);
  uint4 u;
  u.x = pk2(f0.x, f0.y); u.y = pk2(f0.z, f0.w);
  u.z = pk2(f1.x, f1.y); u.w = pk2(f1.z, f1.w);
  *(uint4*)(out + i) = u;
}

__global__ __launch_bounds__(256) void build_bias(
    const float* __restrict__ qb, const float* __restrict__ kb,
    const float* __restrict__ vb, float* __restrict__ bias_cat) {
  int i = blockIdx.x * 256 + threadIdx.x;   // 0..8191
  float v = 0.f;
  if (i < 2048) v = qb[i];
  else if (i < 4096) v = kb[i - 2048];
  else if (i < 6144) v = vb[i - 4096];
  bias_cat[i] = v;
}

// ------------------------------------------------- beta (+ hs->bf16) ------
__global__ __launch_bounds__(256) void beta_kernel(
    const float* __restrict__ hs, const float* __restrict__ bw,
    const float* __restrict__ bb, float* __restrict__ beta,
    unsigned short* __restrict__ hsb) {
  __shared__ float row[2048];
  __shared__ float part[16][17];
  const int m = blockIdx.x;
  const float* src = hs + (size_t)m * 2048;
  for (int i = threadIdx.x; i < 512; i += 256)
    ((float4*)row)[i] = ((const float4*)src)[i];
  __syncthreads();
  if (hsb) {  // fused f32->bf16 of this row
    int e = threadIdx.x * 8;
    uint4 u;
    u.x = pk2(row[e], row[e + 1]);     u.y = pk2(row[e + 2], row[e + 3]);
    u.z = pk2(row[e + 4], row[e + 5]); u.w = pk2(row[e + 6], row[e + 7]);
    *(uint4*)(hsb + (size_t)m * 2048 + e) = u;
  }
  const int h = threadIdx.x >> 4, j = threadIdx.x & 15;
  const float* w = bw + h * 2048;
  float s = 0.f;
  #pragma unroll 8
  for (int kk = 0; kk < 128; kk++) {
    int k = j + (kk << 4);
    s += row[k] * w[k];
  }
  part[h][j] = s;
  __syncthreads();
  if (threadIdx.x < 16) {
    int hh = threadIdx.x;
    float t = bb[hh];
    #pragma unroll
    for (int j2 = 0; j2 < 16; j2++) t += part[hh][j2];
    beta[(size_t)m * 16 + hh] = fmaxf(t, 0.f) + log1pf(__expf(-fabsf(t)));
  }
}

// -------------------------------------------- GEMM 256x256, counted vmcnt --
// C[m,n] = sum_k A[m,k]*B[n,k], bf16 in. 512 threads = 8 waves (2Mx4N).
// LDS ring: As/Bs[4 bufs][256 rows][32 cols] bf16 (16KB per matrix per buf).
// Schedule per K-tile t (cur=t&3, nb=(t+3)&3):
//   phase A: issue A-stage(t+3)->buf nb; ds_read A mi0-3 + B ni0-3 (8xb128);
//            setprio(1); 16 MFMA; setprio(0)
//   phase B: issue B-stage(t+3);         ds_read A mi4-7 (4xb128, B in regs);
//            setprio(1); 16 MFMA; setprio(0)
//   boundary (t != NT-1): s_waitcnt vmcnt(8); s_barrier
// vmcnt proof: outstanding at boundary = tiles t+1(4),t+2(4),t+3(4)=12; in-
// order drain to 8 leaves {t+2,t+3} => t+1 confirmed complete everywhere
// after the barrier. Buffer nb was last read at tile t-1 (before the t-1
// boundary barrier), so staging into it during tile t is race-free.
// Tail (t+3>=NT): stage reloads of tile NT-1's columns into the (free) nb
// slot, keeping the accounting uniform; drained by vmcnt(0) before epilogue.
template <int EPI, int N, int K>
__global__ __launch_bounds__(512, 2) void gemm256(
    const unsigned short* __restrict__ A, const unsigned short* __restrict__ Bw,
    const float* __restrict__ bias, const float* __restrict__ beta,
    void* __restrict__ Cv) {
  constexpr int NT = K / 32;
  __shared__ __align__(16) unsigned short As[4 * 8192];
  __shared__ __align__(16) unsigned short Bs[4 * 8192];
  const int tid = threadIdx.x;
  const int m0 = blockIdx.y * 256;
  const int n0 = blockIdx.x * 256;
  const int wid = tid >> 6, lane = tid & 63;
  const int wm = wid >> 2, wn = wid & 3;
  const int quad = lane >> 4, l16 = lane & 15;

  // staging: thread t covers rows trow and trow+128, 16B chunk p=t&3 of the
  // 64B row; source column is the XOR-swizzled chunk l = p ^ ((row>>1)&3).
  // sigma(trow) == sigma(trow+128) since 128 is a multiple of 8.
  const int trow = tid >> 2;
  const int tch = (((tid & 3) ^ ((trow >> 1) & 3)) << 3);  // element offset
  const unsigned short* Ag = A + (size_t)(m0 + trow) * K + tch;
  const unsigned short* Bg = Bw + (size_t)(n0 + trow) * K + tch;

  // ds_read side: physical chunk = quad ^ ((row>>1)&3); base rows are
  // multiples of 8 so (row>>1)&3 == (l16>>1)&3 for all fragments.
  const int chs = ((quad ^ ((l16 >> 1) & 3)) << 4);        // byte offset
  const int a_lane = (wm * 128 + l16) * 64 + chs;
  const int b_lane = (wn * 64 + l16) * 64 + chs;

  f32x4 acc[8][4] = {};

  // prologue: stage tiles 0,1,2 (A,A,B,B per tile, in tile order)
  #pragma unroll
  for (int tt = 0; tt < 3; ++tt) {
    const size_t kk = (size_t)tt * 32;
    unsigned short* la = As + tt * 8192 + tid * 8;
    unsigned short* lb = Bs + tt * 8192 + tid * 8;
    cp16(Ag + kk, la);
    cp16(Ag + (size_t)128 * K + kk, la + 4096);
    cp16(Bg + kk, lb);
    cp16(Bg + (size_t)128 * K + kk, lb + 4096);
  }
  asm volatile("s_waitcnt vmcnt(8)" ::: "memory");   // tile 0 complete
  __builtin_amdgcn_s_barrier();

  for (int t = 0; t < NT; ++t) {
    const int cur = t & 3;
    const int nb = (t + 3) & 3;
    const size_t k3 = (size_t)((t + 3 < NT) ? (t + 3) : (NT - 1)) * 32;
    const char* At = (const char*)As + cur * 16384 + a_lane;
    const char* Bt = (const char*)Bs + cur * 16384 + b_lane;
    unsigned short* la = As + nb * 8192 + tid * 8;
    unsigned short* lb = Bs + nb * 8192 + tid * 8;

    // ---- phase A: stage next A, compute mi 0..3 x ni 0..3 ----
    cp16(Ag + k3, la);
    cp16(Ag + (size_t)128 * K + k3, la + 4096);
    bf16x8 af[4], bfr[4];
    #pragma unroll
    for (int mi = 0; mi < 4; mi++) af[mi] = *(const bf16x8*)(At + mi * 1024);
    #pragma unroll
    for (int ni = 0; ni < 4; ni++) bfr[ni] = *(const bf16x8*)(Bt + ni * 1024);
    __builtin_amdgcn_s_setprio(1);
    #pragma unroll
    for (int mi = 0; mi < 4; mi++)
      #pragma unroll
      for (int ni = 0; ni < 4; ni++)
        acc[mi][ni] = __builtin_amdgcn_mfma_f32_16x16x32_bf16(
            af[mi], bfr[ni], acc[mi][ni], 0, 0, 0);
    __builtin_amdgcn_s_setprio(0);

    // ---- phase B: stage next B, compute mi 4..7 (B frags held in regs) ----
    cp16(Bg + k3, lb);
    cp16(Bg + (size_t)128 * K + k3, lb + 4096);
    #pragma unroll
    for (int mi = 0; mi < 4; mi++) af[mi] = *(const bf16x8*)(At + (4 + mi) * 1024);
    __builtin_amdgcn_s_setprio(1);
    #pragma unroll
    for (int mi = 0; mi < 4; mi++)
      #pragma unroll
      for (int ni = 0; ni < 4; ni++)
        acc[4 + mi][ni] = __builtin_amdgcn_mfma_f32_16x16x32_bf16(
            af[mi], bfr[ni], acc[4 + mi][ni], 0, 0, 0);
    __builtin_amdgcn_s_setprio(0);

    if (t != NT - 1) {
      asm volatile("s_waitcnt vmcnt(8)" ::: "memory");
      __builtin_amdgcn_s_barrier();
    }
  }
  // drain tail garbage stages before LDS goes out of scope / epilogue
  asm volatile("s_waitcnt vmcnt(0)" ::: "memory");

  // epilogue; C/D layout: col=lane&15, row=quad*4+reg
  if (EPI == 0) {
    const int mode = n0 >> 11;              // 0:q 1:k 2:v 3:gate (256 | 2048)
    unsigned short* outp =
        (unsigned short*)Cv + (size_t)mode * ((size_t)16384 * 2048);
    const int head = ((n0 + wn * 64) >> 7) & 15;   // head uniform per wave
    #pragma unroll
    for (int mi = 0; mi < 8; mi++) {
      #pragma unroll
      for (int r = 0; r < 4; r++) {
        const int row = m0 + wm * 128 + mi * 16 + quad * 4 + r;
        const float bsc = (mode == 2) ? beta[(size_t)row * 16 + head] : 1.f;
        #pragma unroll
        for (int ni = 0; ni < 4; ni++) {
          const int col = n0 + wn * 64 + ni * 16 + l16;
          float x = acc[mi][ni][r] + bias[col];
          if (mode == 2) x *= bsc;
          if (mode == 3) x = x / (1.f + __expf(-x));
          outp[(size_t)row * 2048 + (col & 2047)] = f2bf(x);
        }
      }
    }
  } else {
    #pragma unroll
    for (int mi = 0; mi < 8; mi++)
      #pragma unroll
      for (int r = 0; r < 4; r++) {
        const int row = m0 + wm * 128 + mi * 16 + quad * 4 + r;
        #pragma unroll
        for (int ni = 0; ni < 4; ni++) {
          const int col = n0 + wn * 64 + ni * 16 + l16;
          ((float*)Cv)[(size_t)row * N + col] = acc[mi][ni][r] + bias[col];
        }
      }
  }
}

// --------------------------------------------- fallback GEMM (round 1) ----
constexpr int GLDW = 40;
template <int EPI, bool ABF16>
__global__ __launch_bounds__(256) void gemm_bt(
    const void* __restrict__ Av, const float* __restrict__ Bw,
    const float* __restrict__ bias, const float* __restrict__ beta,
    void* __restrict__ Cv, int M, int N, int K) {
  __shared__ unsigned short As[128 * GLDW];
  __shared__ unsigned short Bs[128 * GLDW];
  const int tid = threadIdx.x;
  const int m0 = blockIdx.y * 128;
  const int n0 = blockIdx.x * 128;
  const int wid = tid >> 6, lane = tid & 63;
  const int wm = wid >> 1, wn = wid & 1;
  const int quad = lane >> 4, l16 = lane & 15;
  const int srow = tid >> 1, skh = (tid & 1) << 4;

  f32x4 acc[4][4] = {};
  const float* Bg = Bw + (size_t)(n0 + srow) * K + skh;

  for (int kb = 0; kb < K; kb += 32) {
    if (ABF16) {
      const unsigned short* Ag =
          (const unsigned short*)Av + (size_t)(m0 + srow) * K + kb + skh;
      uint4 u0 = ((const uint4*)Ag)[0];
      uint4 u1 = ((const uint4*)Ag)[1];
      uint4* d = (uint4*)&As[srow * GLDW + skh];
      d[0] = u0; d[1] = u1;
    } else {
      const float* Ag = (const float*)Av + (size_t)(m0 + srow) * K + kb + skh;
      float4 f0 = ((const float4*)Ag)[0];
      float4 f1 = ((const float4*)Ag)[1];
      float4 f2 = ((const float4*)Ag)[2];
      float4 f3 = ((const float4*)Ag)[3];
      unsigned* d = (unsigned*)&As[srow * GLDW + skh];
      d[0] = pk2(f0.x, f0.y); d[1] = pk2(f0.z, f0.w);
      d[2] = pk2(f1.x, f1.y); d[3] = pk2(f1.z, f1.w);
      d[4] = pk2(f2.x, f2.y); d[5] = pk2(f2.z, f2.w);
      d[6] = pk2(f3.x, f3.y); d[7] = pk2(f3.z, f3.w);
    }
    {
      const float* Bgk = Bg + kb;
      float4 f0 = ((const float4*)Bgk)[0];
      float4 f1 = ((const float4*)Bgk)[1];
      float4 f2 = ((const float4*)Bgk)[2];
      float4 f3 = ((const float4*)Bgk)[3];
      unsigned* d = (unsigned*)&Bs[srow * GLDW + skh];
      d[0] = pk2(f0.x, f0.y); d[1] = pk2(f0.z, f0.w);
      d[2] = pk2(f1.x, f1.y); d[3] = pk2(f1.z, f1.w);
      d[4] = pk2(f2.x, f2.y); d[5] = pk2(f2.z, f2.w);
      d[6] = pk2(f3.x, f3.y); d[7] = pk2(f3.z, f3.w);
    }
    __syncthreads();
    bf16x8 af[4], bfr[4];
    #pragma unroll
    for (int mi = 0; mi < 4; mi++)
      af[mi] = *(const bf16x8*)&As[(wm * 64 + mi * 16 + l16) * GLDW + (quad << 3)];
    #pragma unroll
    for (int ni = 0; ni < 4; ni++)
      bfr[ni] = *(const bf16x8*)&Bs[(wn * 64 + ni * 16 + l16) * GLDW + (quad << 3)];
    #pragma unroll
    for (int mi = 0; mi < 4; mi++)
      #pragma unroll
      for (int ni = 0; ni < 4; ni++)
        acc[mi][ni] = __builtin_amdgcn_mfma_f32_16x16x32_bf16(
            af[mi], bfr[ni], acc[mi][ni], 0, 0, 0);
    __syncthreads();
  }

  #pragma unroll
  for (int mi = 0; mi < 4; mi++) {
    #pragma unroll
    for (int r = 0; r < 4; r++) {
      const int row = m0 + wm * 64 + mi * 16 + quad * 4 + r;
      float bsc = 1.f;
      if (EPI == 1) bsc = beta[(size_t)row * 16 + blockIdx.x];
      #pragma unroll
      for (int ni = 0; ni < 4; ni++) {
        const int col = n0 + wn * 64 + ni * 16 + l16;
        float x = acc[mi][ni][r];
        if (EPI != 2) x += bias[col];
        if (EPI == 1) x *= bsc;
        if (EPI == 2) x = x / (1.f + __expf(-x));
        if (EPI == 3)
          ((float*)Cv)[(size_t)row * N + col] = x;
        else
          ((unsigned short*)Cv)[(size_t)row * N + col] = f2bf(x);
      }
    }
  }
}

// ----------------------------------------------------------- attention ----
constexpr int QK_LDW = 132;  // 264B = 66 banks = 2 mod 32: lanes spread
constexpr int GT_LDW = 66;   // 132B = 33 banks = 1 mod 32: write 16-way -> 4-way
constexpr int SS_LDW = 68;   // 136B = 34 banks = 2 mod 32

__global__ __launch_bounds__(256) void attn_kernel(
    const unsigned short* __restrict__ qn, const unsigned short* __restrict__ kn,
    const unsigned short* __restrict__ gvp, const unsigned short* __restrict__ gate,
    unsigned short* __restrict__ y) {
  __shared__ unsigned short qs[64 * QK_LDW];
  __shared__ unsigned short ks[64 * QK_LDW];
  __shared__ unsigned short gst[128 * GT_LDW];
  __shared__ unsigned short Ss[64 * SS_LDW];

  const int tid = threadIdx.x;
  const int m0 = blockIdx.x * 64;
  const int h = blockIdx.y;
  const size_t gbase = (size_t)m0 * 2048 + (size_t)h * 128;

  #pragma unroll
  for (int it = 0; it < 4; it++) {
    int e = tid + it * 256;
    int i = e >> 4;
    int c = (e & 15) << 3;
    size_t g = gbase + (size_t)i * 2048 + c;
    *(uint4*)&qs[i * QK_LDW + c] = *(const uint4*)&qn[g];
    *(uint4*)&ks[i * QK_LDW + c] = *(const uint4*)&kn[g];
    uint4 gvv = *(const uint4*)&gvp[g];
    unsigned short tmp[8];
    *(uint4*)tmp = gvv;
    #pragma unroll
    for (int t = 0; t < 8; t++) gst[(c + t) * GT_LDW + i] = tmp[t];
  }
  __syncthreads();

  {
    const int rr = tid >> 2;
    const int seg = (tid & 3) * 32;
    float ssq = 0.f, ssk = 0.f;
    #pragma unroll
    for (int k2 = 0; k2 < 32; k2 += 2) {
      unsigned uq = *(const unsigned*)&qs[rr * QK_LDW + seg + k2];
      unsigned uk = *(const unsigned*)&ks[rr * QK_LDW + seg + k2];
      float a = bf2f((unsigned short)(uq & 0xffff)), b = bf2f((unsigned short)(uq >> 16));
      float c2 = bf2f((unsigned short)(uk & 0xffff)), d2 = bf2f((unsigned short)(uk >> 16));
      ssq += a * a + b * b;
      ssk += c2 * c2 + d2 * d2;
    }
    ssq += __shfl_xor(ssq, 1); ssq += __shfl_xor(ssq, 2);
    ssk += __shfl_xor(ssk, 1); ssk += __shfl_xor(ssk, 2);
    float iq = rsqrtf(fmaxf(ssq, 1e-24f));
    float ik = rsqrtf(fmaxf(ssk, 1e-24f));
    #pragma unroll
    for (int k2 = 0; k2 < 32; k2 += 2) {
      unsigned uq = *(const unsigned*)&qs[rr * QK_LDW + seg + k2];
      unsigned uk = *(const unsigned*)&ks[rr * QK_LDW + seg + k2];
      float a = bf2f((unsigned short)(uq & 0xffff)), b = bf2f((unsigned short)(uq >> 16));
      float c2 = bf2f((unsigned short)(uk & 0xffff)), d2 = bf2f((unsigned short)(uk >> 16));
      *(unsigned*)&qs[rr * QK_LDW + seg + k2] = pk2(a * iq, b * iq);
      *(unsigned*)&ks[rr * QK_LDW + seg + k2] = pk2(c2 * ik, d2 * ik);
    }
  }
  __syncthreads();

  const int w = tid >> 6;
  const int lane = tid & 63;
  const int quad = lane >> 4, l16 = lane & 15;

  {
    f32x4 acc[4] = {};
    #pragma unroll
    for (int kst = 0; kst < 4; kst++) {
      bf16x8 a = *(const bf16x8*)&qs[(w * 16 + l16) * QK_LDW + kst * 32 + (quad << 3)];
      #pragma unroll
      for (int ni = 0; ni < 4; ni++) {
        bf16x8 b = *(const bf16x8*)&ks[(ni * 16 + l16) * QK_LDW + kst * 32 + (quad << 3)];
        acc[ni] = __builtin_amdgcn_mfma_f32_16x16x32_bf16(a, b, acc[ni], 0, 0, 0);
      }
    }
    #pragma unroll
    for (int ni = 0; ni < 4; ni++)
      #pragma unroll
      for (int r = 0; r < 4; r++) {
        int row = w * 16 + quad * 4 + r;
        int col = ni * 16 + l16;
        float val = (col <= row) ? acc[ni][r] : 0.f;
        Ss[row * SS_LDW + col] = f2bf(val);
      }
  }
  __syncthreads();

  {
    f32x4 acc[8] = {};
    #pragma unroll
    for (int kst = 0; kst < 2; kst++) {
      bf16x8 a = *(const bf16x8*)&Ss[(w * 16 + l16) * SS_LDW + kst * 32 + (quad << 3)];
      #pragma unroll
      for (int nd = 0; nd < 8; nd++) {
        bf16x8 b = *(const bf16x8*)&gst[(nd * 16 + l16) * GT_LDW + kst * 32 + (quad << 3)];
        acc[nd] = __builtin_amdgcn_mfma_f32_16x16x32_bf16(a, b, acc[nd], 0, 0, 0);
      }
    }
    #pragma unroll
    for (int nd = 0; nd < 8; nd++)
      #pragma unroll
      for (int r = 0; r < 4; r++) {
        int row = w * 16 + quad * 4 + r;
        int col = nd * 16 + l16;
        size_t g = gbase + (size_t)row * 2048 + col;
        float gt = bf2f(gate[g]);
        y[g] = f2bf(acc[nd][r] * gt);
      }
  }
}

// --------------------------------------------------------------- launch ---
extern "C" void kernel_launch(void* const* d_in, const int* in_sizes, int n_in,
                              void* d_out, int out_size, void* d_ws, size_t ws_size,
                              hipStream_t stream) {
  const float* hs   = (const float*)d_in[0];
  const float* q_w  = (const float*)d_in[1];
  const float* q_b  = (const float*)d_in[2];
  const float* k_w  = (const float*)d_in[3];
  const float* k_b  = (const float*)d_in[4];
  const float* v_w  = (const float*)d_in[5];
  const float* v_b  = (const float*)d_in[6];
  const float* b_w  = (const float*)d_in[9];
  const float* b_b  = (const float*)d_in[10];
  const float* og_w = (const float*)d_in[11];
  const float* o_w  = (const float*)d_in[12];
  const float* o_b  = (const float*)d_in[13];

  const int M = 16384, K = 2048;
  const size_t MB64 = 67108864;         // one [M,2048] bf16 buffer

  const size_t OFF_HSB  = 4 * MB64;
  const size_t OFF_WCAT = OFF_HSB + MB64;
  const size_t OFF_OWB  = OFF_WCAT + 33554432;
  const size_t OFF_BETA = OFF_OWB + 8388608;
  const size_t OFF_BIAS = OFF_BETA + 1048576;
  const size_t NEED     = OFF_BIAS + 32768;

  char* ws = (char*)d_ws;

  if (ws_size >= NEED) {
    unsigned short* qy   = (unsigned short*)ws;
    unsigned short* knb  = (unsigned short*)(ws + MB64);
    unsigned short* gv   = (unsigned short*)(ws + 2 * MB64);
    unsigned short* gate = (unsigned short*)(ws + 3 * MB64);
    unsigned short* hsb  = (unsigned short*)(ws + OFF_HSB);
    unsigned short* wcat = (unsigned short*)(ws + OFF_WCAT);
    unsigned short* owb  = (unsigned short*)(ws + OFF_OWB);
    float*          beta = (float*)(ws + OFF_BETA);
    float*          bias = (float*)(ws + OFF_BIAS);

    const int NW = 4194304;  // elems per 2048x2048 weight
    cvt_bf16<<<NW / 2048, 256, 0, stream>>>(q_w,  wcat,          NW);
    cvt_bf16<<<NW / 2048, 256, 0, stream>>>(k_w,  wcat + NW,     NW);
    cvt_bf16<<<NW / 2048, 256, 0, stream>>>(v_w,  wcat + 2 * NW, NW);
    cvt_bf16<<<NW / 2048, 256, 0, stream>>>(og_w, wcat + 3 * NW, NW);
    cvt_bf16<<<NW / 2048, 256, 0, stream>>>(o_w,  owb,           NW);
    build_bias<<<32, 256, 0, stream>>>(q_b, k_b, v_b, bias);
    beta_kernel<<<M, 256, 0, stream>>>(hs, b_w, b_b, beta, hsb);  // + hs->bf16

    gemm256<0, 8192, 2048><<<dim3(32, 64), 512, 0, stream>>>(
        hsb, wcat, bias, beta, qy);

    attn_kernel<<<dim3(256, 16), 256, 0, stream>>>(qy, knb, gv, gate, qy);

    gemm256<3, 2048, 2048><<<dim3(8, 64), 512, 0, stream>>>(
        qy, owb, o_b, nullptr, (float*)d_out);
  } else {
    // round-1 fallback (f32 pack staging), known-correct
    unsigned short* qy   = (unsigned short*)ws;
    unsigned short* knb  = (unsigned short*)(ws + MB64);
    unsigned short* gv   = (unsigned short*)(ws + 2 * MB64);
    unsigned short* gate = (unsigned short*)(ws + 3 * MB64);
    float*          beta = (float*)(ws + 4 * MB64);

    beta_kernel<<<M, 256, 0, stream>>>(hs, b_w, b_b, beta, nullptr);
    dim3 gg(16, 128);
    gemm_bt<0, false><<<gg, 256, 0, stream>>>(hs, q_w, q_b, nullptr, qy, M, 2048, K);
    gemm_bt<0, false><<<gg, 256, 0, stream>>>(hs, k_w, k_b, nullptr, knb, M, 2048, K);
    gemm_bt<1, false><<<gg, 256, 0, stream>>>(hs, v_w, v_b, beta, gv, M, 2048, K);
    gemm_bt<2, false><<<gg, 256, 0, stream>>>(hs, og_w, nullptr, nullptr, gate, M, 2048, K);
    attn_kernel<<<dim3(256, 16), 256, 0, stream>>>(qy, knb, gv, gate, qy);
    gemm_bt<3, true><<<gg, 256, 0, stream>>>(qy, o_w, o_b, nullptr, (float*)d_out, M, 2048, K);
  }
}